// Round 13
// baseline (644.712 us; speedup 1.0000x reference)
//
#include <hip/hip_runtime.h>

#define F 128
#define BN_EPS 1e-5f
#define NG 512    // NUM_GRAPHS
#define AL_S 136  // A/t LDS stride in halves (128 k + 8 pad)

typedef __attribute__((ext_vector_type(8))) _Float16 half8;
typedef __attribute__((ext_vector_type(2))) _Float16 half2v;
typedef __attribute__((ext_vector_type(4))) float f32x4;

// ============ bucketed CSR build: buckets of 1024 nodes, L2-local fills ============

__global__ __launch_bounds__(256) void k_bhist(const int* __restrict__ dst,
                                               int* __restrict__ gbcnt, int E)
{
    __shared__ int cnt[256];
    const int t = threadIdx.x;
    cnt[t] = 0;
    __syncthreads();
    const int base = blockIdx.x * 4096;
#pragma unroll
    for (int i = 0; i < 16; ++i) {
        int e = base + t + i * 256;
        if (e < E) atomicAdd(&cnt[dst[e] >> 10], 1);
    }
    __syncthreads();
    if (cnt[t]) atomicAdd(&gbcnt[t], cnt[t]);
}

__global__ void k_bscan(const int* __restrict__ gbcnt, int* __restrict__ gcur,
                        int* __restrict__ gbase, int NB)
{
    __shared__ int c[257];
    const int t = threadIdx.x;
    if (t < NB) c[t] = gbcnt[t];
    __syncthreads();
    if (t == 0) {
        int s = 0;
        for (int b = 0; b < NB; ++b) { int v = c[b]; c[b] = s; s += v; }
        c[NB] = s;
    }
    __syncthreads();
    if (t < NB) gcur[t] = c[t];
    if (t <= NB) gbase[t] = c[t];
}

__global__ __launch_bounds__(256) void k_bin(const int* __restrict__ src,
                                             const int* __restrict__ dst,
                                             int* __restrict__ gcur,
                                             int* __restrict__ pairs, int E)
{
    __shared__ int cnt[256], bse[256], lcur[256];
    const int t = threadIdx.x;
    cnt[t] = 0;
    __syncthreads();
    const int base = blockIdx.x * 4096;
    int d[16];
#pragma unroll
    for (int i = 0; i < 16; ++i) {
        int e = base + t + i * 256;
        d[i] = (e < E) ? dst[e] : -1;
        if (d[i] >= 0) atomicAdd(&cnt[d[i] >> 10], 1);
    }
    __syncthreads();
    if (cnt[t]) bse[t] = atomicAdd(&gcur[t], cnt[t]);
    lcur[t] = 0;
    __syncthreads();
#pragma unroll
    for (int i = 0; i < 16; ++i) {
        int e = base + t + i * 256;
        if (e < E) {
            int b = d[i] >> 10;
            int r = atomicAdd(&lcur[b], 1);
            pairs[bse[b] + r] = ((d[i] & 1023) << 18) | src[e];
        }
    }
}

__global__ __launch_bounds__(256) void k_csr(const int* __restrict__ pairs,
                                             const int* __restrict__ gbase,
                                             int* __restrict__ rowptr,
                                             int* __restrict__ esrc, int N)
{
    __shared__ int deg[1024];
    __shared__ int scn[256];
    const int b = blockIdx.x, t = threadIdx.x;
    const int pb = gbase[b], pe = gbase[b + 1];
    const int node0 = b << 10;
    for (int i = t; i < 1024; i += 256) deg[i] = 0;
    __syncthreads();
    for (int i = pb + t; i < pe; i += 256) atomicAdd(&deg[pairs[i] >> 18], 1);
    __syncthreads();
    int s0 = deg[t * 4], s1 = deg[t * 4 + 1], s2 = deg[t * 4 + 2], s3 = deg[t * 4 + 3];
    int s = s0 + s1 + s2 + s3;
    scn[t] = s;
    __syncthreads();
    for (int off = 1; off < 256; off <<= 1) {
        int u = (t >= off) ? scn[t - off] : 0;
        __syncthreads();
        if (t >= off) scn[t] += u;
        __syncthreads();
    }
    int excl = scn[t] - s;
    int c0 = pb + excl, c1 = c0 + s0, c2 = c1 + s1, c3 = c2 + s2;
    __syncthreads();
    deg[t * 4] = c0; deg[t * 4 + 1] = c1; deg[t * 4 + 2] = c2; deg[t * 4 + 3] = c3;
    int n0 = node0 + t * 4;
    if (n0 + 3 < N) *(int4*)(rowptr + n0) = make_int4(c0, c1, c2, c3);
    else {
        int cc[4] = {c0, c1, c2, c3};
        for (int k = 0; k < 4; ++k) if (n0 + k < N) rowptr[n0 + k] = cc[k];
    }
    __syncthreads();
    for (int i = pb + t; i < pe; i += 256) {
        int p = pairs[i];
        int pos = atomicAdd(&deg[p >> 18], 1);
        esrc[pos] = p & 0x3ffff;
    }
    if (b == gridDim.x - 1 && t == 0) rowptr[N] = pe;
}

// ======= merged one-time prep: wconv (blocks 0..47), gptr (48..50), x2h (51..) =======
__global__ __launch_bounds__(256) void k_prep(const float* __restrict__ W1,
                                              const float* __restrict__ W2,
                                              _Float16* __restrict__ Wt,
                                              const int* __restrict__ batch,
                                              int* __restrict__ gptr,
                                              const float* __restrict__ x,
                                              _Float16* __restrict__ hh,
                                              int N, long n8)
{
    const int b = blockIdx.x, t = threadIdx.x;
    if (b < 48) {
        int m = b >> 3, cg = b & 7;
        const float* Wsrc = (m < 3) ? (W1 + (size_t)m * F * F)
                                    : (W2 + (size_t)(m - 3) * F * F);
        int col = cg * 16 + (t >> 4);
        int k8  = (t & 15) * 8;
        half8 o;
#pragma unroll
        for (int j = 0; j < 8; ++j) o[j] = (_Float16)Wsrc[(size_t)(k8 + j) * F + col];
        *(half8*)(Wt + (size_t)m * F * F + (size_t)col * F + k8) = o;
    } else if (b < 51) {
        int g = (b - 48) * 256 + t;
        if (g > NG) return;
        int lo = 0, hi = N;
        while (lo < hi) {
            int mid = (lo + hi) >> 1;
            if (batch[mid] < g) lo = mid + 1; else hi = mid;
        }
        gptr[g] = lo;
    } else {
        long i = (long)(b - 51) * 256 + t;
        if (i >= n8) return;
        float4 a = *(const float4*)(x + i * 8);
        float4 c = *(const float4*)(x + i * 8 + 4);
        half8 o;
        o[0] = (_Float16)a.x; o[1] = (_Float16)a.y; o[2] = (_Float16)a.z; o[3] = (_Float16)a.w;
        o[4] = (_Float16)c.x; o[5] = (_Float16)c.y; o[6] = (_Float16)c.z; o[7] = (_Float16)c.w;
        *(half8*)(hh + i * 8) = o;
    }
}

// ===== fused BN(prev) + gather + MLP: Z = relu(relu(z0@W1+b1)@W2+b2) =====
// z0 = a_prev ⊙ (Zp[n] + Σ Zp[src]) + (deg+1)·c_prev  (a=1,c=0 for layer 0).
// 64 rows/block, launch_bounds(256,8): 19.4KB LDS + VGPR<=64 -> up to 8 blk/CU
// (~24-32 waves/CU resident) with unroll-4 gather -> ~2x outstanding loads vs
// the 128-row shape. W frags direct from L2-resident Wt.
__global__ __launch_bounds__(256, 8) void k_gmlp(
    const _Float16* __restrict__ Zp,
    const int* __restrict__ rowptr, const int* __restrict__ esrc,
    const _Float16* __restrict__ W1t, const float* __restrict__ b1,
    const _Float16* __restrict__ W2t, const float* __restrict__ b2,
    _Float16* __restrict__ Z, int N, float* __restrict__ stats,
    const float* __restrict__ pstats, const float* __restrict__ pgamma,
    const float* __restrict__ pbeta, float invN)
{
    __shared__ _Float16 Al[64 * AL_S];
    __shared__ float coefs[256];
    __shared__ float scratch[256];
    const int t = threadIdx.x;
    const int row0 = blockIdx.x << 6;
    const int wave = t >> 6, lane = t & 63;
    const int wr = wave >> 1, wc = wave & 1;
    const int lrow = lane & 15, quad = lane >> 4;
    const int colbase = wc * 64 + lrow;
    const int l16 = t & 15;
    const half8* h8 = (const half8*)Zp;

    // ---- BN coefs of PREVIOUS layer (identity for layer 0)
    if (t < F) {
        float a = 1.f, c = 0.f;
        if (pstats) {
            float mean = pstats[t] * invN;
            float var  = pstats[F + t] * invN - mean * mean;
            a = pgamma[t] * rsqrtf(var + BN_EPS);
            c = pbeta[t] - mean * a;
        }
        coefs[t]     = a;
        coefs[F + t] = c;
    }
    __syncthreads();

    // ---- phase 1: gather z0 rows into Al (4 passes x 16 nodes, 16 lanes/node)
#pragma unroll
    for (int p = 0; p < 4; ++p) {
        int row = p * 16 + (t >> 4);
        int n = row0 + row;
        half8 o = {0, 0, 0, 0, 0, 0, 0, 0};
        if (n < N) {
            float a[8], b[8];
            half8 v = h8[(size_t)n * 16 + l16];
#pragma unroll
            for (int k = 0; k < 8; ++k) { a[k] = (float)v[k]; b[k] = 0.f; }
            const int beg = rowptr[n], end = rowptr[n + 1];
            int j = beg;
            for (; j + 4 <= end; j += 4) {          // 4 b128 gathers in flight
                int s0 = esrc[j], s1 = esrc[j + 1], s2 = esrc[j + 2], s3 = esrc[j + 3];
                half8 u0 = h8[(size_t)s0 * 16 + l16];
                half8 u1 = h8[(size_t)s1 * 16 + l16];
                half8 u2 = h8[(size_t)s2 * 16 + l16];
                half8 u3 = h8[(size_t)s3 * 16 + l16];
#pragma unroll
                for (int k = 0; k < 8; ++k) {
                    a[k] += (float)u0[k]; b[k] += (float)u1[k];
                    a[k] += (float)u2[k]; b[k] += (float)u3[k];
                }
            }
            for (; j < end; ++j) {
                half8 u = h8[(size_t)esrc[j] * 16 + l16];
#pragma unroll
                for (int k = 0; k < 8; ++k) a[k] += (float)u[k];
            }
            float degp1 = (float)(end - beg + 1);
            // fold prev-layer BN: coefs read from LDS (saves 16 VGPRs)
#pragma unroll
            for (int k = 0; k < 8; ++k)
                o[k] = (_Float16)fmaf(coefs[l16 * 8 + k], a[k] + b[k],
                                      degp1 * coefs[F + l16 * 8 + k]);
        }
        *(half8*)(Al + row * AL_S + l16 * 8) = o;
    }

    f32x4 acc[2][4];
#pragma unroll
    for (int i = 0; i < 2; ++i)
#pragma unroll
        for (int j = 0; j < 4; ++j) acc[i][j] = (f32x4){0.f, 0.f, 0.f, 0.f};

    __syncthreads();

    // ---- GEMM1: A from LDS, W1 frags direct from global
#pragma unroll
    for (int kb = 0; kb < 2; ++kb)
#pragma unroll
        for (int kc = 0; kc < 2; ++kc) {
            half8 af[2], bfr[4];
#pragma unroll
            for (int j = 0; j < 4; ++j)
                bfr[j] = *(const half8*)(W1t + (size_t)(wc * 64 + j * 16 + lrow) * F
                                         + (kb << 6) + kc * 32 + quad * 8);
#pragma unroll
            for (int i = 0; i < 2; ++i)
                af[i] = *(half8*)(Al + (wr * 32 + i * 16 + lrow) * AL_S
                                  + (kb << 6) + kc * 32 + quad * 8);
#pragma unroll
            for (int i = 0; i < 2; ++i)
#pragma unroll
                for (int j = 0; j < 4; ++j)
                    acc[i][j] = __builtin_amdgcn_mfma_f32_16x16x32_f16(
                        af[i], bfr[j], acc[i][j], 0, 0, 0);
        }

    // ---- t = relu(acc + b1) -> Al
    float bv[4];
#pragma unroll
    for (int j = 0; j < 4; ++j) bv[j] = b1[colbase + j * 16];
    __syncthreads();
#pragma unroll
    for (int i = 0; i < 2; ++i)
#pragma unroll
        for (int r = 0; r < 4; ++r) {
            int row = wr * 32 + i * 16 + quad * 4 + r;
#pragma unroll
            for (int j = 0; j < 4; ++j)
                Al[row * AL_S + colbase + j * 16] =
                    (_Float16)fmaxf(acc[i][j][r] + bv[j], 0.f);
        }

#pragma unroll
    for (int i = 0; i < 2; ++i)
#pragma unroll
        for (int j = 0; j < 4; ++j) acc[i][j] = (f32x4){0.f, 0.f, 0.f, 0.f};

    __syncthreads();

    // ---- GEMM2: t from LDS, W2 frags direct from global
#pragma unroll
    for (int kb = 0; kb < 2; ++kb)
#pragma unroll
        for (int kc = 0; kc < 2; ++kc) {
            half8 af[2], bfr[4];
#pragma unroll
            for (int j = 0; j < 4; ++j)
                bfr[j] = *(const half8*)(W2t + (size_t)(wc * 64 + j * 16 + lrow) * F
                                         + (kb << 6) + kc * 32 + quad * 8);
#pragma unroll
            for (int i = 0; i < 2; ++i)
                af[i] = *(half8*)(Al + (wr * 32 + i * 16 + lrow) * AL_S
                                  + (kb << 6) + kc * 32 + quad * 8);
#pragma unroll
            for (int i = 0; i < 2; ++i)
#pragma unroll
                for (int j = 0; j < 4; ++j)
                    acc[i][j] = __builtin_amdgcn_mfma_f32_16x16x32_f16(
                        af[i], bfr[j], acc[i][j], 0, 0, 0);
        }

    // ---- epilogue: z = relu(acc + b2); fp32 BN stats; z -> Al -> coalesced store
#pragma unroll
    for (int j = 0; j < 4; ++j) bv[j] = b2[colbase + j * 16];

    float s[4], q[4];
#pragma unroll
    for (int j = 0; j < 4; ++j) { s[j] = 0.f; q[j] = 0.f; }

    __syncthreads();
    scratch[t] = 0.f;
#pragma unroll
    for (int i = 0; i < 2; ++i)
#pragma unroll
        for (int r = 0; r < 4; ++r) {
            int row = wr * 32 + i * 16 + quad * 4 + r;
            bool ok = (row0 + row) < N;
#pragma unroll
            for (int j = 0; j < 4; ++j) {
                float u = fmaxf(acc[i][j][r] + bv[j], 0.f);
                Al[row * AL_S + colbase + j * 16] = (_Float16)u;
                if (ok) { s[j] += u; q[j] += u * u; }
            }
        }
    __syncthreads();
#pragma unroll
    for (int j = 0; j < 4; ++j) {
        atomicAdd(&scratch[colbase + j * 16], s[j]);
        atomicAdd(&scratch[F + colbase + j * 16], q[j]);
    }
#pragma unroll
    for (int i = 0; i < 4; ++i) {
        int idx = t + (i << 8);
        int row = idx >> 4;
        int k8  = (idx & 15) << 3;
        int gr = row0 + row;
        if (gr < N)
            *(half8*)(Z + (size_t)gr * F + k8) = *(half8*)(Al + row * AL_S + k8);
    }
    __syncthreads();
    if (t < F) {
        atomicAdd(&stats[t],     scratch[t]);
        atomicAdd(&stats[F + t], scratch[F + t]);
    }
}

// ---- pool only: coefs from stats, read z, BN in regs, segmented reduce, write out ----
__global__ __launch_bounds__(256) void k_pool(
    const _Float16* __restrict__ zh, const float* __restrict__ stats,
    const float* __restrict__ gamma, const float* __restrict__ beta, float invN,
    const int* __restrict__ gptr, float* __restrict__ outL)
{
    __shared__ float coefs[256];
    const int g = blockIdx.x;
    const int t = threadIdx.x;
    if (t < F) {
        float mean = stats[t] * invN;
        float var  = stats[F + t] * invN - mean * mean;
        float a = gamma[t] * rsqrtf(var + BN_EPS);
        coefs[t]     = a;
        coefs[F + t] = beta[t] - mean * a;
    }
    __syncthreads();

    const int beg = gptr[g], end = gptr[g + 1];
    const int wave = t >> 6, lane = t & 63;

    float2 a = ((const float2*)coefs)[lane];
    float2 c = ((const float2*)(coefs + F))[lane];
    float2 acc = make_float2(0.f, 0.f);
    const half2v* z2 = (const half2v*)zh;

    for (int n = beg + wave; n < end; n += 4) {
        half2v v = z2[(size_t)n * 64 + lane];
        acc.x += fmaf((float)v.x, a.x, c.x);
        acc.y += fmaf((float)v.y, a.y, c.y);
    }

    __shared__ float2 red[4][64];
    red[wave][lane] = acc;
    __syncthreads();
    if (wave == 0) {
        float2 r = red[0][lane];
        r.x += red[1][lane].x + red[2][lane].x + red[3][lane].x;
        r.y += red[1][lane].y + red[2][lane].y + red[3][lane].y;
        ((float2*)outL)[(size_t)g * 192 + lane] = r;
    }
}

extern "C" void kernel_launch(void* const* d_in, const int* in_sizes, int n_in,
                              void* d_out, int out_size, void* d_ws, size_t ws_size,
                              hipStream_t stream)
{
    const float* x     = (const float*)d_in[0];
    const int*   ei    = (const int*)  d_in[1];
    const int*   batch = (const int*)  d_in[2];
    const float* W1    = (const float*)d_in[3];
    const float* b1    = (const float*)d_in[4];
    const float* W2    = (const float*)d_in[5];
    const float* b2    = (const float*)d_in[6];
    const float* gamma = (const float*)d_in[7];
    const float* beta  = (const float*)d_in[8];

    const int N = in_sizes[0] / F;      // 100000
    const int E = in_sizes[1] / 2;      // 1600000
    const int* src = ei;
    const int* dst = ei + E;
    float* out = (float*)d_out;

    const size_t NF = (size_t)N * F;
    _Float16* P0 = (_Float16*)d_ws;             // x16 / Z1
    _Float16* P1 = P0 + NF;                     // Z0 / Z2
    _Float16* Wt = P1 + NF;                     // 6*F*F fp16
    float* stats  = (float*)(Wt + 6 * F * F);   // 768
    int*   gbcnt  = (int*)(stats + 768);        // 256
    int*   pairs  = gbcnt + 256;                // E (packed local10<<18|src)
    int*   esrc   = pairs + E;                  // E
    int*   rowptr = esrc + E;                   // N+1
    int*   gptr   = rowptr + N + 1;             // NG+1
    int*   gcur   = gptr + NG + 1;              // 256
    int*   gbase  = gcur + 256;                 // 257

    hipMemsetAsync(stats, 0, (768 + 256) * sizeof(float), stream);

    const int NB = (N + 1023) >> 10;
    const int ebk = (E + 4095) / 4096;
    const long n8 = (long)(NF / 8);

    k_bhist<<<ebk, 256, 0, stream>>>(dst, gbcnt, E);
    k_bscan<<<1, 256, 0, stream>>>(gbcnt, gcur, gbase, NB);
    k_bin  <<<ebk, 256, 0, stream>>>(src, dst, gcur, pairs, E);
    k_csr  <<<NB, 256, 0, stream>>>(pairs, gbase, rowptr, esrc, N);
    k_prep <<<(int)(51 + (n8 + 255) / 256), 256, 0, stream>>>(
        W1, W2, Wt, batch, gptr, x, P0, N, n8);

    const float invN = 1.0f / (float)N;
    const int mlp_grid = (N + 63) / 64;

    _Float16* Hin = P0;
    _Float16* Zout = P1;
    for (int L = 0; L < 3; ++L) {
        k_gmlp<<<mlp_grid, 256, 0, stream>>>(
            Hin, rowptr, esrc,
            Wt + (size_t)L * F * F, b1 + L * F,
            Wt + (size_t)(3 + L) * F * F, b2 + L * F,
            Zout, N, stats + L * 256,
            L ? stats + (size_t)(L - 1) * 256 : nullptr,
            L ? gamma + (size_t)(L - 1) * F : nullptr,
            L ? beta + (size_t)(L - 1) * F : nullptr, invN);
        k_pool<<<NG, 256, 0, stream>>>(Zout, stats + L * 256, gamma + L * F,
                                       beta + L * F, invN, gptr, out + L * F);
        _Float16* tmp = Hin; Hin = Zout; Zout = tmp;
    }
}

// Round 14
// 590.972 us; speedup vs baseline: 1.0909x; 1.0909x over previous
//
#include <hip/hip_runtime.h>

#define F 128
#define BN_EPS 1e-5f
#define NG 512    // NUM_GRAPHS
#define AL_S 136  // A/t LDS stride in halves (128 k + 8 pad)

typedef __attribute__((ext_vector_type(8))) _Float16 half8;
typedef __attribute__((ext_vector_type(2))) _Float16 half2v;
typedef __attribute__((ext_vector_type(4))) float f32x4;

// ============ bucketed CSR build: buckets of 1024 nodes, L2-local fills ============

__global__ __launch_bounds__(256) void k_bhist(const int* __restrict__ dst,
                                               int* __restrict__ gbcnt, int E)
{
    __shared__ int cnt[256];
    const int t = threadIdx.x;
    cnt[t] = 0;
    __syncthreads();
    const int base = blockIdx.x * 4096;
#pragma unroll
    for (int i = 0; i < 16; ++i) {
        int e = base + t + i * 256;
        if (e < E) atomicAdd(&cnt[dst[e] >> 10], 1);
    }
    __syncthreads();
    if (cnt[t]) atomicAdd(&gbcnt[t], cnt[t]);
}

__global__ void k_bscan(const int* __restrict__ gbcnt, int* __restrict__ gcur,
                        int* __restrict__ gbase, int NB)
{
    __shared__ int c[257];
    const int t = threadIdx.x;
    if (t < NB) c[t] = gbcnt[t];
    __syncthreads();
    if (t == 0) {
        int s = 0;
        for (int b = 0; b < NB; ++b) { int v = c[b]; c[b] = s; s += v; }
        c[NB] = s;
    }
    __syncthreads();
    if (t < NB) gcur[t] = c[t];
    if (t <= NB) gbase[t] = c[t];
}

__global__ __launch_bounds__(256) void k_bin(const int* __restrict__ src,
                                             const int* __restrict__ dst,
                                             int* __restrict__ gcur,
                                             int* __restrict__ pairs, int E)
{
    __shared__ int cnt[256], bse[256], lcur[256];
    const int t = threadIdx.x;
    cnt[t] = 0;
    __syncthreads();
    const int base = blockIdx.x * 4096;
    int d[16];
#pragma unroll
    for (int i = 0; i < 16; ++i) {
        int e = base + t + i * 256;
        d[i] = (e < E) ? dst[e] : -1;
        if (d[i] >= 0) atomicAdd(&cnt[d[i] >> 10], 1);
    }
    __syncthreads();
    if (cnt[t]) bse[t] = atomicAdd(&gcur[t], cnt[t]);
    lcur[t] = 0;
    __syncthreads();
#pragma unroll
    for (int i = 0; i < 16; ++i) {
        int e = base + t + i * 256;
        if (e < E) {
            int b = d[i] >> 10;
            int r = atomicAdd(&lcur[b], 1);
            pairs[bse[b] + r] = ((d[i] & 1023) << 18) | src[e];
        }
    }
}

__global__ __launch_bounds__(256) void k_csr(const int* __restrict__ pairs,
                                             const int* __restrict__ gbase,
                                             int* __restrict__ rowptr,
                                             int* __restrict__ esrc, int N)
{
    __shared__ int deg[1024];
    __shared__ int scn[256];
    const int b = blockIdx.x, t = threadIdx.x;
    const int pb = gbase[b], pe = gbase[b + 1];
    const int node0 = b << 10;
    for (int i = t; i < 1024; i += 256) deg[i] = 0;
    __syncthreads();
    for (int i = pb + t; i < pe; i += 256) atomicAdd(&deg[pairs[i] >> 18], 1);
    __syncthreads();
    int s0 = deg[t * 4], s1 = deg[t * 4 + 1], s2 = deg[t * 4 + 2], s3 = deg[t * 4 + 3];
    int s = s0 + s1 + s2 + s3;
    scn[t] = s;
    __syncthreads();
    for (int off = 1; off < 256; off <<= 1) {
        int u = (t >= off) ? scn[t - off] : 0;
        __syncthreads();
        if (t >= off) scn[t] += u;
        __syncthreads();
    }
    int excl = scn[t] - s;
    int c0 = pb + excl, c1 = c0 + s0, c2 = c1 + s1, c3 = c2 + s2;
    __syncthreads();
    deg[t * 4] = c0; deg[t * 4 + 1] = c1; deg[t * 4 + 2] = c2; deg[t * 4 + 3] = c3;
    int n0 = node0 + t * 4;
    if (n0 + 3 < N) *(int4*)(rowptr + n0) = make_int4(c0, c1, c2, c3);
    else {
        int cc[4] = {c0, c1, c2, c3};
        for (int k = 0; k < 4; ++k) if (n0 + k < N) rowptr[n0 + k] = cc[k];
    }
    __syncthreads();
    for (int i = pb + t; i < pe; i += 256) {
        int p = pairs[i];
        int pos = atomicAdd(&deg[p >> 18], 1);
        esrc[pos] = p & 0x3ffff;
    }
    if (b == gridDim.x - 1 && t == 0) rowptr[N] = pe;
}

// ======= merged one-time prep: wconv (blocks 0..47), gptr (48..50), x2h (51..) =======
__global__ __launch_bounds__(256) void k_prep(const float* __restrict__ W1,
                                              const float* __restrict__ W2,
                                              _Float16* __restrict__ Wt,
                                              const int* __restrict__ batch,
                                              int* __restrict__ gptr,
                                              const float* __restrict__ x,
                                              _Float16* __restrict__ hh,
                                              int N, long n8)
{
    const int b = blockIdx.x, t = threadIdx.x;
    if (b < 48) {
        int m = b >> 3, cg = b & 7;
        const float* Wsrc = (m < 3) ? (W1 + (size_t)m * F * F)
                                    : (W2 + (size_t)(m - 3) * F * F);
        int col = cg * 16 + (t >> 4);
        int k8  = (t & 15) * 8;
        half8 o;
#pragma unroll
        for (int j = 0; j < 8; ++j) o[j] = (_Float16)Wsrc[(size_t)(k8 + j) * F + col];
        *(half8*)(Wt + (size_t)m * F * F + (size_t)col * F + k8) = o;
    } else if (b < 51) {
        int g = (b - 48) * 256 + t;
        if (g > NG) return;
        int lo = 0, hi = N;
        while (lo < hi) {
            int mid = (lo + hi) >> 1;
            if (batch[mid] < g) lo = mid + 1; else hi = mid;
        }
        gptr[g] = lo;
    } else {
        long i = (long)(b - 51) * 256 + t;
        if (i >= n8) return;
        float4 a = *(const float4*)(x + i * 8);
        float4 c = *(const float4*)(x + i * 8 + 4);
        half8 o;
        o[0] = (_Float16)a.x; o[1] = (_Float16)a.y; o[2] = (_Float16)a.z; o[3] = (_Float16)a.w;
        o[4] = (_Float16)c.x; o[5] = (_Float16)c.y; o[6] = (_Float16)c.z; o[7] = (_Float16)c.w;
        *(half8*)(hh + i * 8) = o;
    }
}

// ===== fused BN(prev) + gather + MLP: Z = relu(relu(z0@W1+b1)@W2+b2) =====
// z0 = a_prev ⊙ (Zp[n] + Σ Zp[src]) + (deg+1)·c_prev  (a=1,c=0 for layer 0).
// 64 rows/block + launch_bounds(256,4): small LDS (19.4KB -> up to 8 blk/CU,
// grid 1563 ≈ 6 resident) at the PROVEN VGPR budget (count-64; (256,6/8)
// clamps caused serialization/spills in R11/R13). Gather unroll-4.
__global__ __launch_bounds__(256, 4) void k_gmlp(
    const _Float16* __restrict__ Zp,
    const int* __restrict__ rowptr, const int* __restrict__ esrc,
    const _Float16* __restrict__ W1t, const float* __restrict__ b1,
    const _Float16* __restrict__ W2t, const float* __restrict__ b2,
    _Float16* __restrict__ Z, int N, float* __restrict__ stats,
    const float* __restrict__ pstats, const float* __restrict__ pgamma,
    const float* __restrict__ pbeta, float invN)
{
    __shared__ _Float16 Al[64 * AL_S];
    __shared__ float coefs[256];
    __shared__ float scratch[256];
    const int t = threadIdx.x;
    const int row0 = blockIdx.x << 6;
    const int wave = t >> 6, lane = t & 63;
    const int wr = wave >> 1, wc = wave & 1;
    const int lrow = lane & 15, quad = lane >> 4;
    const int colbase = wc * 64 + lrow;
    const int l16 = t & 15;
    const half8* h8 = (const half8*)Zp;

    // ---- BN coefs of PREVIOUS layer (identity for layer 0)
    if (t < F) {
        float a = 1.f, c = 0.f;
        if (pstats) {
            float mean = pstats[t] * invN;
            float var  = pstats[F + t] * invN - mean * mean;
            a = pgamma[t] * rsqrtf(var + BN_EPS);
            c = pbeta[t] - mean * a;
        }
        coefs[t]     = a;
        coefs[F + t] = c;
    }
    __syncthreads();

    // ---- phase 1: gather z0 rows into Al (4 passes x 16 nodes, 16 lanes/node)
    float ca[8], cc[8];
    {
        f32x4 a0 = *(f32x4*)(coefs + l16 * 8);
        f32x4 a1 = *(f32x4*)(coefs + l16 * 8 + 4);
        f32x4 c0 = *(f32x4*)(coefs + F + l16 * 8);
        f32x4 c1 = *(f32x4*)(coefs + F + l16 * 8 + 4);
#pragma unroll
        for (int k = 0; k < 4; ++k) {
            ca[k] = a0[k]; ca[k + 4] = a1[k];
            cc[k] = c0[k]; cc[k + 4] = c1[k];
        }
    }
#pragma unroll
    for (int p = 0; p < 4; ++p) {
        int row = p * 16 + (t >> 4);
        int n = row0 + row;
        half8 o = {0, 0, 0, 0, 0, 0, 0, 0};
        if (n < N) {
            float a[8], b[8];
            half8 v = h8[(size_t)n * 16 + l16];
#pragma unroll
            for (int k = 0; k < 8; ++k) { a[k] = (float)v[k]; b[k] = 0.f; }
            const int beg = rowptr[n], end = rowptr[n + 1];
            int j = beg;
            for (; j + 4 <= end; j += 4) {          // 4 b128 gathers in flight
                int s0 = esrc[j], s1 = esrc[j + 1], s2 = esrc[j + 2], s3 = esrc[j + 3];
                half8 u0 = h8[(size_t)s0 * 16 + l16];
                half8 u1 = h8[(size_t)s1 * 16 + l16];
                half8 u2 = h8[(size_t)s2 * 16 + l16];
                half8 u3 = h8[(size_t)s3 * 16 + l16];
#pragma unroll
                for (int k = 0; k < 8; ++k) {
                    a[k] += (float)u0[k]; b[k] += (float)u1[k];
                    a[k] += (float)u2[k]; b[k] += (float)u3[k];
                }
            }
            for (; j < end; ++j) {
                half8 u = h8[(size_t)esrc[j] * 16 + l16];
#pragma unroll
                for (int k = 0; k < 8; ++k) a[k] += (float)u[k];
            }
            float degp1 = (float)(end - beg + 1);
#pragma unroll
            for (int k = 0; k < 8; ++k)
                o[k] = (_Float16)fmaf(ca[k], a[k] + b[k], degp1 * cc[k]);
        }
        *(half8*)(Al + row * AL_S + l16 * 8) = o;
    }

    f32x4 acc[2][4];
#pragma unroll
    for (int i = 0; i < 2; ++i)
#pragma unroll
        for (int j = 0; j < 4; ++j) acc[i][j] = (f32x4){0.f, 0.f, 0.f, 0.f};

    __syncthreads();

    // ---- GEMM1: A from LDS, W1 frags direct from global
#pragma unroll
    for (int kb = 0; kb < 2; ++kb)
#pragma unroll
        for (int kc = 0; kc < 2; ++kc) {
            half8 af[2], bfr[4];
#pragma unroll
            for (int j = 0; j < 4; ++j)
                bfr[j] = *(const half8*)(W1t + (size_t)(wc * 64 + j * 16 + lrow) * F
                                         + (kb << 6) + kc * 32 + quad * 8);
#pragma unroll
            for (int i = 0; i < 2; ++i)
                af[i] = *(half8*)(Al + (wr * 32 + i * 16 + lrow) * AL_S
                                  + (kb << 6) + kc * 32 + quad * 8);
#pragma unroll
            for (int i = 0; i < 2; ++i)
#pragma unroll
                for (int j = 0; j < 4; ++j)
                    acc[i][j] = __builtin_amdgcn_mfma_f32_16x16x32_f16(
                        af[i], bfr[j], acc[i][j], 0, 0, 0);
        }

    // ---- t = relu(acc + b1) -> Al
    float bv[4];
#pragma unroll
    for (int j = 0; j < 4; ++j) bv[j] = b1[colbase + j * 16];
    __syncthreads();
#pragma unroll
    for (int i = 0; i < 2; ++i)
#pragma unroll
        for (int r = 0; r < 4; ++r) {
            int row = wr * 32 + i * 16 + quad * 4 + r;
#pragma unroll
            for (int j = 0; j < 4; ++j)
                Al[row * AL_S + colbase + j * 16] =
                    (_Float16)fmaxf(acc[i][j][r] + bv[j], 0.f);
        }

#pragma unroll
    for (int i = 0; i < 2; ++i)
#pragma unroll
        for (int j = 0; j < 4; ++j) acc[i][j] = (f32x4){0.f, 0.f, 0.f, 0.f};

    __syncthreads();

    // ---- GEMM2: t from LDS, W2 frags direct from global
#pragma unroll
    for (int kb = 0; kb < 2; ++kb)
#pragma unroll
        for (int kc = 0; kc < 2; ++kc) {
            half8 af[2], bfr[4];
#pragma unroll
            for (int j = 0; j < 4; ++j)
                bfr[j] = *(const half8*)(W2t + (size_t)(wc * 64 + j * 16 + lrow) * F
                                         + (kb << 6) + kc * 32 + quad * 8);
#pragma unroll
            for (int i = 0; i < 2; ++i)
                af[i] = *(half8*)(Al + (wr * 32 + i * 16 + lrow) * AL_S
                                  + (kb << 6) + kc * 32 + quad * 8);
#pragma unroll
            for (int i = 0; i < 2; ++i)
#pragma unroll
                for (int j = 0; j < 4; ++j)
                    acc[i][j] = __builtin_amdgcn_mfma_f32_16x16x32_f16(
                        af[i], bfr[j], acc[i][j], 0, 0, 0);
        }

    // ---- epilogue: z = relu(acc + b2); fp32 BN stats; z -> Al -> coalesced store
#pragma unroll
    for (int j = 0; j < 4; ++j) bv[j] = b2[colbase + j * 16];

    float s[4], q[4];
#pragma unroll
    for (int j = 0; j < 4; ++j) { s[j] = 0.f; q[j] = 0.f; }

    __syncthreads();
    scratch[t] = 0.f;
#pragma unroll
    for (int i = 0; i < 2; ++i)
#pragma unroll
        for (int r = 0; r < 4; ++r) {
            int row = wr * 32 + i * 16 + quad * 4 + r;
            bool ok = (row0 + row) < N;
#pragma unroll
            for (int j = 0; j < 4; ++j) {
                float u = fmaxf(acc[i][j][r] + bv[j], 0.f);
                Al[row * AL_S + colbase + j * 16] = (_Float16)u;
                if (ok) { s[j] += u; q[j] += u * u; }
            }
        }
    __syncthreads();
#pragma unroll
    for (int j = 0; j < 4; ++j) {
        atomicAdd(&scratch[colbase + j * 16], s[j]);
        atomicAdd(&scratch[F + colbase + j * 16], q[j]);
    }
#pragma unroll
    for (int i = 0; i < 4; ++i) {
        int idx = t + (i << 8);
        int row = idx >> 4;
        int k8  = (idx & 15) << 3;
        int gr = row0 + row;
        if (gr < N)
            *(half8*)(Z + (size_t)gr * F + k8) = *(half8*)(Al + row * AL_S + k8);
    }
    __syncthreads();
    if (t < F) {
        atomicAdd(&stats[t],     scratch[t]);
        atomicAdd(&stats[F + t], scratch[F + t]);
    }
}

// ---- pool only: coefs from stats, read z, BN in regs, segmented reduce, write out ----
__global__ __launch_bounds__(256) void k_pool(
    const _Float16* __restrict__ zh, const float* __restrict__ stats,
    const float* __restrict__ gamma, const float* __restrict__ beta, float invN,
    const int* __restrict__ gptr, float* __restrict__ outL)
{
    __shared__ float coefs[256];
    const int g = blockIdx.x;
    const int t = threadIdx.x;
    if (t < F) {
        float mean = stats[t] * invN;
        float var  = stats[F + t] * invN - mean * mean;
        float a = gamma[t] * rsqrtf(var + BN_EPS);
        coefs[t]     = a;
        coefs[F + t] = beta[t] - mean * a;
    }
    __syncthreads();

    const int beg = gptr[g], end = gptr[g + 1];
    const int wave = t >> 6, lane = t & 63;

    float2 a = ((const float2*)coefs)[lane];
    float2 c = ((const float2*)(coefs + F))[lane];
    float2 acc = make_float2(0.f, 0.f);
    const half2v* z2 = (const half2v*)zh;

    for (int n = beg + wave; n < end; n += 4) {
        half2v v = z2[(size_t)n * 64 + lane];
        acc.x += fmaf((float)v.x, a.x, c.x);
        acc.y += fmaf((float)v.y, a.y, c.y);
    }

    __shared__ float2 red[4][64];
    red[wave][lane] = acc;
    __syncthreads();
    if (wave == 0) {
        float2 r = red[0][lane];
        r.x += red[1][lane].x + red[2][lane].x + red[3][lane].x;
        r.y += red[1][lane].y + red[2][lane].y + red[3][lane].y;
        ((float2*)outL)[(size_t)g * 192 + lane] = r;
    }
}

extern "C" void kernel_launch(void* const* d_in, const int* in_sizes, int n_in,
                              void* d_out, int out_size, void* d_ws, size_t ws_size,
                              hipStream_t stream)
{
    const float* x     = (const float*)d_in[0];
    const int*   ei    = (const int*)  d_in[1];
    const int*   batch = (const int*)  d_in[2];
    const float* W1    = (const float*)d_in[3];
    const float* b1    = (const float*)d_in[4];
    const float* W2    = (const float*)d_in[5];
    const float* b2    = (const float*)d_in[6];
    const float* gamma = (const float*)d_in[7];
    const float* beta  = (const float*)d_in[8];

    const int N = in_sizes[0] / F;      // 100000
    const int E = in_sizes[1] / 2;      // 1600000
    const int* src = ei;
    const int* dst = ei + E;
    float* out = (float*)d_out;

    const size_t NF = (size_t)N * F;
    _Float16* P0 = (_Float16*)d_ws;             // x16 / Z1
    _Float16* P1 = P0 + NF;                     // Z0 / Z2
    _Float16* Wt = P1 + NF;                     // 6*F*F fp16
    float* stats  = (float*)(Wt + 6 * F * F);   // 768
    int*   gbcnt  = (int*)(stats + 768);        // 256
    int*   pairs  = gbcnt + 256;                // E (packed local10<<18|src)
    int*   esrc   = pairs + E;                  // E
    int*   rowptr = esrc + E;                   // N+1
    int*   gptr   = rowptr + N + 1;             // NG+1
    int*   gcur   = gptr + NG + 1;              // 256
    int*   gbase  = gcur + 256;                 // 257

    hipMemsetAsync(stats, 0, (768 + 256) * sizeof(float), stream);

    const int NB = (N + 1023) >> 10;
    const int ebk = (E + 4095) / 4096;
    const long n8 = (long)(NF / 8);

    k_bhist<<<ebk, 256, 0, stream>>>(dst, gbcnt, E);
    k_bscan<<<1, 256, 0, stream>>>(gbcnt, gcur, gbase, NB);
    k_bin  <<<ebk, 256, 0, stream>>>(src, dst, gcur, pairs, E);
    k_csr  <<<NB, 256, 0, stream>>>(pairs, gbase, rowptr, esrc, N);
    k_prep <<<(int)(51 + (n8 + 255) / 256), 256, 0, stream>>>(
        W1, W2, Wt, batch, gptr, x, P0, N, n8);

    const float invN = 1.0f / (float)N;
    const int mlp_grid = (N + 63) / 64;

    _Float16* Hin = P0;
    _Float16* Zout = P1;
    for (int L = 0; L < 3; ++L) {
        k_gmlp<<<mlp_grid, 256, 0, stream>>>(
            Hin, rowptr, esrc,
            Wt + (size_t)L * F * F, b1 + L * F,
            Wt + (size_t)(3 + L) * F * F, b2 + L * F,
            Zout, N, stats + L * 256,
            L ? stats + (size_t)(L - 1) * 256 : nullptr,
            L ? gamma + (size_t)(L - 1) * F : nullptr,
            L ? beta + (size_t)(L - 1) * F : nullptr, invN);
        k_pool<<<NG, 256, 0, stream>>>(Zout, stats + L * 256, gamma + L * F,
                                       beta + L * F, invN, gptr, out + L * F);
        _Float16* tmp = Hin; Hin = Zout; Zout = tmp;
    }
}

// Round 15
// 473.045 us; speedup vs baseline: 1.3629x; 1.2493x over previous
//
#include <hip/hip_runtime.h>

#define F 128
#define BN_EPS 1e-5f
#define NG 512    // NUM_GRAPHS
#define AL_S 136  // A/t LDS stride in halves (128 k + 8 pad)

typedef __attribute__((ext_vector_type(8))) _Float16 half8;
typedef __attribute__((ext_vector_type(4))) float f32x4;

// ============ bucketed CSR build: buckets of 1024 nodes, L2-local fills ============

__global__ __launch_bounds__(256) void k_bhist(const int* __restrict__ dst,
                                               int* __restrict__ gbcnt, int E)
{
    __shared__ int cnt[256];
    const int t = threadIdx.x;
    cnt[t] = 0;
    __syncthreads();
    const int base = blockIdx.x * 4096;
#pragma unroll
    for (int i = 0; i < 16; ++i) {
        int e = base + t + i * 256;
        if (e < E) atomicAdd(&cnt[dst[e] >> 10], 1);
    }
    __syncthreads();
    if (cnt[t]) atomicAdd(&gbcnt[t], cnt[t]);
}

__global__ void k_bscan(const int* __restrict__ gbcnt, int* __restrict__ gcur,
                        int* __restrict__ gbase, int NB)
{
    __shared__ int c[257];
    const int t = threadIdx.x;
    if (t < NB) c[t] = gbcnt[t];
    __syncthreads();
    if (t == 0) {
        int s = 0;
        for (int b = 0; b < NB; ++b) { int v = c[b]; c[b] = s; s += v; }
        c[NB] = s;
    }
    __syncthreads();
    if (t < NB) gcur[t] = c[t];
    if (t <= NB) gbase[t] = c[t];
}

__global__ __launch_bounds__(256) void k_bin(const int* __restrict__ src,
                                             const int* __restrict__ dst,
                                             int* __restrict__ gcur,
                                             int* __restrict__ pairs, int E)
{
    __shared__ int cnt[256], bse[256], lcur[256];
    const int t = threadIdx.x;
    cnt[t] = 0;
    __syncthreads();
    const int base = blockIdx.x * 4096;
    int d[16];
#pragma unroll
    for (int i = 0; i < 16; ++i) {
        int e = base + t + i * 256;
        d[i] = (e < E) ? dst[e] : -1;
        if (d[i] >= 0) atomicAdd(&cnt[d[i] >> 10], 1);
    }
    __syncthreads();
    if (cnt[t]) bse[t] = atomicAdd(&gcur[t], cnt[t]);
    lcur[t] = 0;
    __syncthreads();
#pragma unroll
    for (int i = 0; i < 16; ++i) {
        int e = base + t + i * 256;
        if (e < E) {
            int b = d[i] >> 10;
            int r = atomicAdd(&lcur[b], 1);
            pairs[bse[b] + r] = ((d[i] & 1023) << 18) | src[e];
        }
    }
}

__global__ __launch_bounds__(256) void k_csr(const int* __restrict__ pairs,
                                             const int* __restrict__ gbase,
                                             int* __restrict__ rowptr,
                                             int* __restrict__ esrc, int N)
{
    __shared__ int deg[1024];
    __shared__ int scn[256];
    const int b = blockIdx.x, t = threadIdx.x;
    const int pb = gbase[b], pe = gbase[b + 1];
    const int node0 = b << 10;
    for (int i = t; i < 1024; i += 256) deg[i] = 0;
    __syncthreads();
    for (int i = pb + t; i < pe; i += 256) atomicAdd(&deg[pairs[i] >> 18], 1);
    __syncthreads();
    int s0 = deg[t * 4], s1 = deg[t * 4 + 1], s2 = deg[t * 4 + 2], s3 = deg[t * 4 + 3];
    int s = s0 + s1 + s2 + s3;
    scn[t] = s;
    __syncthreads();
    for (int off = 1; off < 256; off <<= 1) {
        int u = (t >= off) ? scn[t - off] : 0;
        __syncthreads();
        if (t >= off) scn[t] += u;
        __syncthreads();
    }
    int excl = scn[t] - s;
    int c0 = pb + excl, c1 = c0 + s0, c2 = c1 + s1, c3 = c2 + s2;
    __syncthreads();
    deg[t * 4] = c0; deg[t * 4 + 1] = c1; deg[t * 4 + 2] = c2; deg[t * 4 + 3] = c3;
    int n0 = node0 + t * 4;
    if (n0 + 3 < N) *(int4*)(rowptr + n0) = make_int4(c0, c1, c2, c3);
    else {
        int cc[4] = {c0, c1, c2, c3};
        for (int k = 0; k < 4; ++k) if (n0 + k < N) rowptr[n0 + k] = cc[k];
    }
    __syncthreads();
    for (int i = pb + t; i < pe; i += 256) {
        int p = pairs[i];
        int pos = atomicAdd(&deg[p >> 18], 1);
        esrc[pos] = p & 0x3ffff;
    }
    if (b == gridDim.x - 1 && t == 0) rowptr[N] = pe;
}

// ======= merged one-time prep: wconv (blocks 0..47), gptr (48..50), x2h (51..) =======
__global__ __launch_bounds__(256) void k_prep(const float* __restrict__ W1,
                                              const float* __restrict__ W2,
                                              _Float16* __restrict__ Wt,
                                              const int* __restrict__ batch,
                                              int* __restrict__ gptr,
                                              const float* __restrict__ x,
                                              _Float16* __restrict__ hh,
                                              int N, long n8)
{
    const int b = blockIdx.x, t = threadIdx.x;
    if (b < 48) {
        int m = b >> 3, cg = b & 7;
        const float* Wsrc = (m < 3) ? (W1 + (size_t)m * F * F)
                                    : (W2 + (size_t)(m - 3) * F * F);
        int col = cg * 16 + (t >> 4);
        int k8  = (t & 15) * 8;
        half8 o;
#pragma unroll
        for (int j = 0; j < 8; ++j) o[j] = (_Float16)Wsrc[(size_t)(k8 + j) * F + col];
        *(half8*)(Wt + (size_t)m * F * F + (size_t)col * F + k8) = o;
    } else if (b < 51) {
        int g = (b - 48) * 256 + t;
        if (g > NG) return;
        int lo = 0, hi = N;
        while (lo < hi) {
            int mid = (lo + hi) >> 1;
            if (batch[mid] < g) lo = mid + 1; else hi = mid;
        }
        gptr[g] = lo;
    } else {
        long i = (long)(b - 51) * 256 + t;
        if (i >= n8) return;
        float4 a = *(const float4*)(x + i * 8);
        float4 c = *(const float4*)(x + i * 8 + 4);
        half8 o;
        o[0] = (_Float16)a.x; o[1] = (_Float16)a.y; o[2] = (_Float16)a.z; o[3] = (_Float16)a.w;
        o[4] = (_Float16)c.x; o[5] = (_Float16)c.y; o[6] = (_Float16)c.z; o[7] = (_Float16)c.w;
        *(half8*)(hh + i * 8) = o;
    }
}

// ===== fused BN(prev) + gather + MLP + graph-pool: Z = relu(relu(z0@W1+b1)@W2+b2) =====
// z0 = a_prev ⊙ (Zp[n] + Σ Zp[src]) + (deg+1)·c_prev  (a=1,c=0 for layer 0).
// Pool: raw fp32 z sums per graph accumulated in epilogue (Σ(a z+c) = aΣz+cnt·c,
// affine applied later in k_fin). 128 rows/block, (256,4) — the proven VGPR-64 shape.
__global__ __launch_bounds__(256, 4) void k_gmlp(
    const _Float16* __restrict__ Zp,
    const int* __restrict__ rowptr, const int* __restrict__ esrc,
    const _Float16* __restrict__ W1t, const float* __restrict__ b1,
    const _Float16* __restrict__ W2t, const float* __restrict__ b2,
    _Float16* __restrict__ Z, int N, float* __restrict__ stats,
    const float* __restrict__ pstats, const float* __restrict__ pgamma,
    const float* __restrict__ pbeta, float invN,
    const int* __restrict__ batch, float* __restrict__ gsumL)
{
    __shared__ _Float16 Al[128 * AL_S];
    __shared__ float coefs[256];        // phase 1: BN coefs; later: batch ids (int)
    __shared__ float scratch[256];
    __shared__ float poolbuf[512];      // 4 graph slots x 128 cols
    const int t = threadIdx.x;
    const int row0 = blockIdx.x << 7;
    const int wave = t >> 6, lane = t & 63;
    const int wr = wave >> 1, wc = wave & 1;
    const int lrow = lane & 15, quad = lane >> 4;
    const int colbase = wc * 64 + lrow;
    const int l16 = t & 15;
    const half8* h8 = (const half8*)Zp;

    // ---- BN coefs of PREVIOUS layer (identity for layer 0)
    if (t < F) {
        float a = 1.f, c = 0.f;
        if (pstats) {
            float mean = pstats[t] * invN;
            float var  = pstats[F + t] * invN - mean * mean;
            a = pgamma[t] * rsqrtf(var + BN_EPS);
            c = pbeta[t] - mean * a;
        }
        coefs[t]     = a;
        coefs[F + t] = c;
    }
    __syncthreads();

    // ---- phase 1: gather z0 rows into Al (8 passes x 16 nodes, 16 lanes/node)
    float ca[8], cc[8];
    {
        f32x4 a0 = *(f32x4*)(coefs + l16 * 8);
        f32x4 a1 = *(f32x4*)(coefs + l16 * 8 + 4);
        f32x4 c0 = *(f32x4*)(coefs + F + l16 * 8);
        f32x4 c1 = *(f32x4*)(coefs + F + l16 * 8 + 4);
#pragma unroll
        for (int k = 0; k < 4; ++k) {
            ca[k] = a0[k]; ca[k + 4] = a1[k];
            cc[k] = c0[k]; cc[k + 4] = c1[k];
        }
    }
#pragma unroll
    for (int p = 0; p < 8; ++p) {
        int row = p * 16 + (t >> 4);
        int n = row0 + row;
        half8 o = {0, 0, 0, 0, 0, 0, 0, 0};
        if (n < N) {
            float a[8], b[8];
            half8 v = h8[(size_t)n * 16 + l16];
#pragma unroll
            for (int k = 0; k < 8; ++k) { a[k] = (float)v[k]; b[k] = 0.f; }
            const int beg = rowptr[n], end = rowptr[n + 1];
            int j = beg;
            for (; j + 8 <= end; j += 8) {
                int s0 = esrc[j],     s1 = esrc[j + 1];
                int s2 = esrc[j + 2], s3 = esrc[j + 3];
                int s4 = esrc[j + 4], s5 = esrc[j + 5];
                int s6 = esrc[j + 6], s7 = esrc[j + 7];
                half8 u0 = h8[(size_t)s0 * 16 + l16];
                half8 u1 = h8[(size_t)s1 * 16 + l16];
                half8 u2 = h8[(size_t)s2 * 16 + l16];
                half8 u3 = h8[(size_t)s3 * 16 + l16];
                half8 u4 = h8[(size_t)s4 * 16 + l16];
                half8 u5 = h8[(size_t)s5 * 16 + l16];
                half8 u6 = h8[(size_t)s6 * 16 + l16];
                half8 u7 = h8[(size_t)s7 * 16 + l16];
#pragma unroll
                for (int k = 0; k < 8; ++k) {
                    a[k] += (float)u0[k]; b[k] += (float)u1[k];
                    a[k] += (float)u2[k]; b[k] += (float)u3[k];
                    a[k] += (float)u4[k]; b[k] += (float)u5[k];
                    a[k] += (float)u6[k]; b[k] += (float)u7[k];
                }
            }
            for (; j + 4 <= end; j += 4) {
                int s0 = esrc[j], s1 = esrc[j + 1], s2 = esrc[j + 2], s3 = esrc[j + 3];
                half8 u0 = h8[(size_t)s0 * 16 + l16];
                half8 u1 = h8[(size_t)s1 * 16 + l16];
                half8 u2 = h8[(size_t)s2 * 16 + l16];
                half8 u3 = h8[(size_t)s3 * 16 + l16];
#pragma unroll
                for (int k = 0; k < 8; ++k) {
                    a[k] += (float)u0[k]; b[k] += (float)u1[k];
                    a[k] += (float)u2[k]; b[k] += (float)u3[k];
                }
            }
            for (; j < end; ++j) {
                half8 u = h8[(size_t)esrc[j] * 16 + l16];
#pragma unroll
                for (int k = 0; k < 8; ++k) a[k] += (float)u[k];
            }
            float degp1 = (float)(end - beg + 1);
#pragma unroll
            for (int k = 0; k < 8; ++k)
                o[k] = (_Float16)fmaf(ca[k], a[k] + b[k], degp1 * cc[k]);
        }
        *(half8*)(Al + row * AL_S + l16 * 8) = o;
    }

    f32x4 acc[4][4];
#pragma unroll
    for (int i = 0; i < 4; ++i)
#pragma unroll
        for (int j = 0; j < 4; ++j) acc[i][j] = (f32x4){0.f, 0.f, 0.f, 0.f};

    __syncthreads();

    // coefs LDS is dead now (cached in ca/cc): reuse as batch-id cache; zero poolbuf
    int* bl = (int*)coefs;
    if (t < 128) { int gr = row0 + t; bl[t] = (gr < N) ? batch[gr] : -1; }
    poolbuf[t] = 0.f; poolbuf[t + 256] = 0.f;

    // ---- GEMM1: A from LDS, W1 frags direct from global
#pragma unroll
    for (int kb = 0; kb < 2; ++kb)
#pragma unroll
        for (int kc = 0; kc < 2; ++kc) {
            half8 af[4], bfr[4];
#pragma unroll
            for (int j = 0; j < 4; ++j)
                bfr[j] = *(const half8*)(W1t + (size_t)(wc * 64 + j * 16 + lrow) * F
                                         + (kb << 6) + kc * 32 + quad * 8);
#pragma unroll
            for (int i = 0; i < 4; ++i)
                af[i] = *(half8*)(Al + (wr * 64 + i * 16 + lrow) * AL_S
                                  + (kb << 6) + kc * 32 + quad * 8);
#pragma unroll
            for (int i = 0; i < 4; ++i)
#pragma unroll
                for (int j = 0; j < 4; ++j)
                    acc[i][j] = __builtin_amdgcn_mfma_f32_16x16x32_f16(
                        af[i], bfr[j], acc[i][j], 0, 0, 0);
        }

    // ---- t = relu(acc + b1) -> Al
    float bv[4];
#pragma unroll
    for (int j = 0; j < 4; ++j) bv[j] = b1[colbase + j * 16];
    __syncthreads();
#pragma unroll
    for (int i = 0; i < 4; ++i)
#pragma unroll
        for (int r = 0; r < 4; ++r) {
            int row = wr * 64 + i * 16 + quad * 4 + r;
#pragma unroll
            for (int j = 0; j < 4; ++j)
                Al[row * AL_S + colbase + j * 16] =
                    (_Float16)fmaxf(acc[i][j][r] + bv[j], 0.f);
        }

#pragma unroll
    for (int i = 0; i < 4; ++i)
#pragma unroll
        for (int j = 0; j < 4; ++j) acc[i][j] = (f32x4){0.f, 0.f, 0.f, 0.f};

    __syncthreads();

    // ---- GEMM2: t from LDS, W2 frags direct from global
#pragma unroll
    for (int kb = 0; kb < 2; ++kb)
#pragma unroll
        for (int kc = 0; kc < 2; ++kc) {
            half8 af[4], bfr[4];
#pragma unroll
            for (int j = 0; j < 4; ++j)
                bfr[j] = *(const half8*)(W2t + (size_t)(wc * 64 + j * 16 + lrow) * F
                                         + (kb << 6) + kc * 32 + quad * 8);
#pragma unroll
            for (int i = 0; i < 4; ++i)
                af[i] = *(half8*)(Al + (wr * 64 + i * 16 + lrow) * AL_S
                                  + (kb << 6) + kc * 32 + quad * 8);
#pragma unroll
            for (int i = 0; i < 4; ++i)
#pragma unroll
                for (int j = 0; j < 4; ++j)
                    acc[i][j] = __builtin_amdgcn_mfma_f32_16x16x32_f16(
                        af[i], bfr[j], acc[i][j], 0, 0, 0);
        }

    // ---- epilogue: z = relu(acc + b2); stats + raw-z graph pooling; optional Z store
#pragma unroll
    for (int j = 0; j < 4; ++j) bv[j] = b2[colbase + j * 16];

    float s[4], q[4], p[4];
#pragma unroll
    for (int j = 0; j < 4; ++j) { s[j] = 0.f; q[j] = 0.f; p[j] = 0.f; }

    __syncthreads();                    // all GEMM2 reads of Al done
    scratch[t] = 0.f;
    const int g0 = bl[0];
    int gcur = -1;
#pragma unroll
    for (int i = 0; i < 4; ++i)
#pragma unroll
        for (int r = 0; r < 4; ++r) {
            int row = wr * 64 + i * 16 + quad * 4 + r;   // ascending over (i,r)
            bool ok = (row0 + row) < N;
            if (ok) {
                int g = bl[row];
                if (g != gcur) {
                    if (gcur >= 0) {                     // flush partial
                        int slot = gcur - g0;
                        if (slot >= 0 && slot < 4) {
#pragma unroll
                            for (int j = 0; j < 4; ++j)
                                atomicAdd(&poolbuf[slot * F + colbase + j * 16], p[j]);
                        } else {
#pragma unroll
                            for (int j = 0; j < 4; ++j)
                                atomicAdd(&gsumL[(size_t)gcur * F + colbase + j * 16], p[j]);
                        }
#pragma unroll
                        for (int j = 0; j < 4; ++j) p[j] = 0.f;
                    }
                    gcur = g;
                }
            }
#pragma unroll
            for (int j = 0; j < 4; ++j) {
                float u = fmaxf(acc[i][j][r] + bv[j], 0.f);
                Al[row * AL_S + colbase + j * 16] = (_Float16)u;
                if (ok) { s[j] += u; q[j] += u * u; p[j] += u; }
            }
        }
    if (gcur >= 0) {                                     // final flush
        int slot = gcur - g0;
        if (slot >= 0 && slot < 4) {
#pragma unroll
            for (int j = 0; j < 4; ++j)
                atomicAdd(&poolbuf[slot * F + colbase + j * 16], p[j]);
        } else {
#pragma unroll
            for (int j = 0; j < 4; ++j)
                atomicAdd(&gsumL[(size_t)gcur * F + colbase + j * 16], p[j]);
        }
    }
    __syncthreads();                    // Al z-tile + scratch init + poolbuf complete
#pragma unroll
    for (int j = 0; j < 4; ++j) {
        atomicAdd(&scratch[colbase + j * 16], s[j]);
        atomicAdd(&scratch[F + colbase + j * 16], q[j]);
    }
    // drain poolbuf -> gsum (2 slots per thread)
#pragma unroll
    for (int sp = 0; sp < 2; ++sp) {
        int idx = t + sp * 256;
        int slot = idx >> 7, col = idx & 127;
        int g = g0 + slot;
        if (g >= 0 && g < NG)
            atomicAdd(&gsumL[(size_t)g * F + col], poolbuf[idx]);
    }
    if (Z) {
#pragma unroll
        for (int i = 0; i < 8; ++i) {   // coalesced b128 store of z
            int idx = t + (i << 8);
            int row = idx >> 4;
            int k8  = (idx & 15) << 3;
            int gr = row0 + row;
            if (gr < N)
                *(half8*)(Z + (size_t)gr * F + k8) = *(half8*)(Al + row * AL_S + k8);
        }
    }
    __syncthreads();                    // scratch atomics done
    if (t < F) {
        atomicAdd(&stats[t],     scratch[t]);
        atomicAdd(&stats[F + t], scratch[F + t]);
    }
}

// ---- finalize: out[g][L*128+f] = a_Lf * gsum[L][g][f] + cnt_g * c_Lf ----
__global__ __launch_bounds__(384) void k_fin(
    const float* __restrict__ stats, const float* __restrict__ gamma,
    const float* __restrict__ beta, const float* __restrict__ gsum,
    const int* __restrict__ gptr, float invN, float* __restrict__ out)
{
    const int g = blockIdx.x, t = threadIdx.x;
    const int L = t >> 7, f = t & 127;
    float cnt = (float)(gptr[g + 1] - gptr[g]);
    float mean = stats[L * 256 + f] * invN;
    float var  = stats[L * 256 + F + f] * invN - mean * mean;
    float a = gamma[L * F + f] * rsqrtf(var + BN_EPS);
    float c = beta[L * F + f] - mean * a;
    out[(size_t)g * 384 + L * F + f] =
        fmaf(a, gsum[((size_t)L * NG + g) * F + f], cnt * c);
}

extern "C" void kernel_launch(void* const* d_in, const int* in_sizes, int n_in,
                              void* d_out, int out_size, void* d_ws, size_t ws_size,
                              hipStream_t stream)
{
    const float* x     = (const float*)d_in[0];
    const int*   ei    = (const int*)  d_in[1];
    const int*   batch = (const int*)  d_in[2];
    const float* W1    = (const float*)d_in[3];
    const float* b1    = (const float*)d_in[4];
    const float* W2    = (const float*)d_in[5];
    const float* b2    = (const float*)d_in[6];
    const float* gamma = (const float*)d_in[7];
    const float* beta  = (const float*)d_in[8];

    const int N = in_sizes[0] / F;      // 100000
    const int E = in_sizes[1] / 2;      // 1600000
    const int* src = ei;
    const int* dst = ei + E;
    float* out = (float*)d_out;

    const size_t NF = (size_t)N * F;
    _Float16* P0 = (_Float16*)d_ws;             // x16 / Z1
    _Float16* P1 = P0 + NF;                     // Z0 / Z2
    _Float16* Wt = P1 + NF;                     // 6*F*F fp16
    float* stats  = (float*)(Wt + 6 * F * F);   // 768
    int*   gbcnt  = (int*)(stats + 768);        // 256
    float* gsum   = (float*)(gbcnt + 256);      // 3*NG*F = 196608
    int*   pairs  = (int*)(gsum + 3 * NG * F);  // E (packed local10<<18|src)
    int*   esrc   = pairs + E;                  // E
    int*   rowptr = esrc + E;                   // N+1
    int*   gptr   = rowptr + N + 1;             // NG+1
    int*   gcur   = gptr + NG + 1;              // 256
    int*   gbase  = gcur + 256;                 // 257

    // one memset covers stats + gbcnt + gsum (contiguous)
    hipMemsetAsync(stats, 0, (768 + 256 + 3 * NG * F) * sizeof(float), stream);

    const int NB = (N + 1023) >> 10;
    const int ebk = (E + 4095) / 4096;
    const long n8 = (long)(NF / 8);

    k_bhist<<<ebk, 256, 0, stream>>>(dst, gbcnt, E);
    k_bscan<<<1, 256, 0, stream>>>(gbcnt, gcur, gbase, NB);
    k_bin  <<<ebk, 256, 0, stream>>>(src, dst, gcur, pairs, E);
    k_csr  <<<NB, 256, 0, stream>>>(pairs, gbase, rowptr, esrc, N);
    k_prep <<<(int)(51 + (n8 + 255) / 256), 256, 0, stream>>>(
        W1, W2, Wt, batch, gptr, x, P0, N, n8);

    const float invN = 1.0f / (float)N;
    const int mlp_grid = (N + 127) / 128;

    _Float16* Hin = P0;
    _Float16* Zout = P1;
    for (int L = 0; L < 3; ++L) {
        k_gmlp<<<mlp_grid, 256, 0, stream>>>(
            Hin, rowptr, esrc,
            Wt + (size_t)L * F * F, b1 + L * F,
            Wt + (size_t)(3 + L) * F * F, b2 + L * F,
            (L < 2) ? Zout : nullptr,            // last layer: z only pooled, not stored
            N, stats + L * 256,
            L ? stats + (size_t)(L - 1) * 256 : nullptr,
            L ? gamma + (size_t)(L - 1) * F : nullptr,
            L ? beta + (size_t)(L - 1) * F : nullptr, invN,
            batch, gsum + (size_t)L * NG * F);
        _Float16* tmp = Hin; Hin = Zout; Zout = tmp;
    }
    k_fin<<<NG, 384, 0, stream>>>(stats, gamma, beta, gsum, gptr, invN, out);
}

// Round 16
// 454.605 us; speedup vs baseline: 1.4182x; 1.0406x over previous
//
#include <hip/hip_runtime.h>

#define F 128
#define BN_EPS 1e-5f
#define NG 512     // NUM_GRAPHS
#define AL_S 136   // A/t LDS stride in halves (128 k + 8 pad)
#define CAP 24576  // per-bucket edge capacity (mean 16.3K, sigma 128 -> 60+ sigma margin)

typedef __attribute__((ext_vector_type(8))) _Float16 half8;
typedef __attribute__((ext_vector_type(4))) float f32x4;

// ====== bin edges into fixed-capacity buckets + merged one-time prep ======
// blocks [0,ebk): bin (dst,src)->pairs ; [ebk,ebk+48): wconv ;
// [ebk+48,ebk+51): gptr ; rest: x2h
__global__ __launch_bounds__(256) void k_bin_prep(
    const int* __restrict__ src, const int* __restrict__ dst,
    int* __restrict__ gcnt, int* __restrict__ pairs, int E, int ebk,
    const float* __restrict__ W1, const float* __restrict__ W2,
    _Float16* __restrict__ Wt, const int* __restrict__ batch,
    int* __restrict__ gptr, const float* __restrict__ x,
    _Float16* __restrict__ hh, int N, long n8)
{
    const int b = blockIdx.x, t = threadIdx.x;
    if (b < ebk) {
        __shared__ int cnt[256], bse[256], lcur[256];
        cnt[t] = 0;
        __syncthreads();
        const int base = b * 4096;
        int d[16];
#pragma unroll
        for (int i = 0; i < 16; ++i) {
            int e = base + t + i * 256;
            d[i] = (e < E) ? dst[e] : -1;
            if (d[i] >= 0) atomicAdd(&cnt[d[i] >> 10], 1);
        }
        __syncthreads();
        if (cnt[t]) bse[t] = t * CAP + atomicAdd(&gcnt[t], cnt[t]);
        lcur[t] = 0;
        __syncthreads();
#pragma unroll
        for (int i = 0; i < 16; ++i) {
            int e = base + t + i * 256;
            if (e < E) {
                int bk = d[i] >> 10;
                int r = atomicAdd(&lcur[bk], 1);
                pairs[bse[bk] + r] = ((d[i] & 1023) << 18) | src[e];
            }
        }
    } else if (b < ebk + 48) {
        int m = (b - ebk) >> 3, cg = (b - ebk) & 7;
        const float* Wsrc = (m < 3) ? (W1 + (size_t)m * F * F)
                                    : (W2 + (size_t)(m - 3) * F * F);
        int col = cg * 16 + (t >> 4);
        int k8  = (t & 15) * 8;
        half8 o;
#pragma unroll
        for (int j = 0; j < 8; ++j) o[j] = (_Float16)Wsrc[(size_t)(k8 + j) * F + col];
        *(half8*)(Wt + (size_t)m * F * F + (size_t)col * F + k8) = o;
    } else if (b < ebk + 51) {
        int g = (b - ebk - 48) * 256 + t;
        if (g > NG) return;
        int lo = 0, hi = N;
        while (lo < hi) {
            int mid = (lo + hi) >> 1;
            if (batch[mid] < g) lo = mid + 1; else hi = mid;
        }
        gptr[g] = lo;
    } else {
        long i = (long)(b - ebk - 51) * 256 + t;
        if (i >= n8) return;
        float4 a = *(const float4*)(x + i * 8);
        float4 c = *(const float4*)(x + i * 8 + 4);
        half8 o;
        o[0] = (_Float16)a.x; o[1] = (_Float16)a.y; o[2] = (_Float16)a.z; o[3] = (_Float16)a.w;
        o[4] = (_Float16)c.x; o[5] = (_Float16)c.y; o[6] = (_Float16)c.z; o[7] = (_Float16)c.w;
        *(half8*)(hh + i * 8) = o;
    }
}

// one block per bucket: hist -> scan -> rbeg/rend + cursor-fill esrc (padded layout)
__global__ __launch_bounds__(256) void k_csr(const int* __restrict__ pairs,
                                             const int* __restrict__ gcnt,
                                             int* __restrict__ rbeg,
                                             int* __restrict__ rend,
                                             int* __restrict__ esrc, int N)
{
    __shared__ int deg[1024];
    __shared__ int scn[256];
    const int b = blockIdx.x, t = threadIdx.x;
    const int pb = b * CAP, pe = pb + gcnt[b];
    const int node0 = b << 10;
    for (int i = t; i < 1024; i += 256) deg[i] = 0;
    __syncthreads();
    for (int i = pb + t; i < pe; i += 256) atomicAdd(&deg[pairs[i] >> 18], 1);
    __syncthreads();
    int s0 = deg[t * 4], s1 = deg[t * 4 + 1], s2 = deg[t * 4 + 2], s3 = deg[t * 4 + 3];
    int s = s0 + s1 + s2 + s3;
    scn[t] = s;
    __syncthreads();
    for (int off = 1; off < 256; off <<= 1) {
        int u = (t >= off) ? scn[t - off] : 0;
        __syncthreads();
        if (t >= off) scn[t] += u;
        __syncthreads();
    }
    int excl = scn[t] - s;
    int c0 = pb + excl, c1 = c0 + s0, c2 = c1 + s1, c3 = c2 + s2;
    __syncthreads();
    deg[t * 4] = c0; deg[t * 4 + 1] = c1; deg[t * 4 + 2] = c2; deg[t * 4 + 3] = c3;
    int n0 = node0 + t * 4;
    if (n0 + 3 < N) {
        *(int4*)(rbeg + n0) = make_int4(c0, c1, c2, c3);
        *(int4*)(rend + n0) = make_int4(c0 + s0, c1 + s1, c2 + s2, c3 + s3);
    } else {
        int cb[4] = {c0, c1, c2, c3};
        int ce[4] = {c0 + s0, c1 + s1, c2 + s2, c3 + s3};
        for (int k = 0; k < 4; ++k)
            if (n0 + k < N) { rbeg[n0 + k] = cb[k]; rend[n0 + k] = ce[k]; }
    }
    __syncthreads();
    for (int i = pb + t; i < pe; i += 256) {
        int p = pairs[i];
        int pos = atomicAdd(&deg[p >> 18], 1);
        esrc[pos] = p & 0x3ffff;
    }
}

// ===== fused BN(prev) + gather + MLP + graph-pool: Z = relu(relu(z0@W1+b1)@W2+b2) =====
// z0 = a_prev ⊙ (Zp[n] + Σ Zp[src]) + (deg+1)·c_prev  (a=1,c=0 for layer 0).
// Pool: raw fp32 z sums per graph in epilogue (Σ(a z+c) = aΣz+cnt·c, affine in k_fin).
// 128 rows/block, (256,4) — the proven VGPR-64 shape (R10-R15 sweep).
__global__ __launch_bounds__(256, 4) void k_gmlp(
    const _Float16* __restrict__ Zp,
    const int* __restrict__ rbeg, const int* __restrict__ rend,
    const int* __restrict__ esrc,
    const _Float16* __restrict__ W1t, const float* __restrict__ b1,
    const _Float16* __restrict__ W2t, const float* __restrict__ b2,
    _Float16* __restrict__ Z, int N, float* __restrict__ stats,
    const float* __restrict__ pstats, const float* __restrict__ pgamma,
    const float* __restrict__ pbeta, float invN,
    const int* __restrict__ batch, float* __restrict__ gsumL)
{
    __shared__ _Float16 Al[128 * AL_S];
    __shared__ float coefs[256];        // phase 1: BN coefs; later: batch ids (int)
    __shared__ float scratch[256];
    __shared__ float poolbuf[512];      // 4 graph slots x 128 cols
    const int t = threadIdx.x;
    const int row0 = blockIdx.x << 7;
    const int wave = t >> 6, lane = t & 63;
    const int wr = wave >> 1, wc = wave & 1;
    const int lrow = lane & 15, quad = lane >> 4;
    const int colbase = wc * 64 + lrow;
    const int l16 = t & 15;
    const half8* h8 = (const half8*)Zp;

    // ---- BN coefs of PREVIOUS layer (identity for layer 0)
    if (t < F) {
        float a = 1.f, c = 0.f;
        if (pstats) {
            float mean = pstats[t] * invN;
            float var  = pstats[F + t] * invN - mean * mean;
            a = pgamma[t] * rsqrtf(var + BN_EPS);
            c = pbeta[t] - mean * a;
        }
        coefs[t]     = a;
        coefs[F + t] = c;
    }
    __syncthreads();

    // ---- phase 1: gather z0 rows into Al (8 passes x 16 nodes, 16 lanes/node)
    float ca[8], cc[8];
    {
        f32x4 a0 = *(f32x4*)(coefs + l16 * 8);
        f32x4 a1 = *(f32x4*)(coefs + l16 * 8 + 4);
        f32x4 c0 = *(f32x4*)(coefs + F + l16 * 8);
        f32x4 c1 = *(f32x4*)(coefs + F + l16 * 8 + 4);
#pragma unroll
        for (int k = 0; k < 4; ++k) {
            ca[k] = a0[k]; ca[k + 4] = a1[k];
            cc[k] = c0[k]; cc[k + 4] = c1[k];
        }
    }
#pragma unroll
    for (int p = 0; p < 8; ++p) {
        int row = p * 16 + (t >> 4);
        int n = row0 + row;
        half8 o = {0, 0, 0, 0, 0, 0, 0, 0};
        if (n < N) {
            float a[8], b[8];
            half8 v = h8[(size_t)n * 16 + l16];
#pragma unroll
            for (int k = 0; k < 8; ++k) { a[k] = (float)v[k]; b[k] = 0.f; }
            const int beg = rbeg[n], end = rend[n];
            int j = beg;
            for (; j + 8 <= end; j += 8) {
                int s0 = esrc[j],     s1 = esrc[j + 1];
                int s2 = esrc[j + 2], s3 = esrc[j + 3];
                int s4 = esrc[j + 4], s5 = esrc[j + 5];
                int s6 = esrc[j + 6], s7 = esrc[j + 7];
                half8 u0 = h8[(size_t)s0 * 16 + l16];
                half8 u1 = h8[(size_t)s1 * 16 + l16];
                half8 u2 = h8[(size_t)s2 * 16 + l16];
                half8 u3 = h8[(size_t)s3 * 16 + l16];
                half8 u4 = h8[(size_t)s4 * 16 + l16];
                half8 u5 = h8[(size_t)s5 * 16 + l16];
                half8 u6 = h8[(size_t)s6 * 16 + l16];
                half8 u7 = h8[(size_t)s7 * 16 + l16];
#pragma unroll
                for (int k = 0; k < 8; ++k) {
                    a[k] += (float)u0[k]; b[k] += (float)u1[k];
                    a[k] += (float)u2[k]; b[k] += (float)u3[k];
                    a[k] += (float)u4[k]; b[k] += (float)u5[k];
                    a[k] += (float)u6[k]; b[k] += (float)u7[k];
                }
            }
            for (; j + 4 <= end; j += 4) {
                int s0 = esrc[j], s1 = esrc[j + 1], s2 = esrc[j + 2], s3 = esrc[j + 3];
                half8 u0 = h8[(size_t)s0 * 16 + l16];
                half8 u1 = h8[(size_t)s1 * 16 + l16];
                half8 u2 = h8[(size_t)s2 * 16 + l16];
                half8 u3 = h8[(size_t)s3 * 16 + l16];
#pragma unroll
                for (int k = 0; k < 8; ++k) {
                    a[k] += (float)u0[k]; b[k] += (float)u1[k];
                    a[k] += (float)u2[k]; b[k] += (float)u3[k];
                }
            }
            for (; j < end; ++j) {
                half8 u = h8[(size_t)esrc[j] * 16 + l16];
#pragma unroll
                for (int k = 0; k < 8; ++k) a[k] += (float)u[k];
            }
            float degp1 = (float)(end - beg + 1);
#pragma unroll
            for (int k = 0; k < 8; ++k)
                o[k] = (_Float16)fmaf(ca[k], a[k] + b[k], degp1 * cc[k]);
        }
        *(half8*)(Al + row * AL_S + l16 * 8) = o;
    }

    f32x4 acc[4][4];
#pragma unroll
    for (int i = 0; i < 4; ++i)
#pragma unroll
        for (int j = 0; j < 4; ++j) acc[i][j] = (f32x4){0.f, 0.f, 0.f, 0.f};

    __syncthreads();

    // coefs LDS dead (cached in ca/cc): reuse as batch-id cache; zero poolbuf
    int* bl = (int*)coefs;
    if (t < 128) { int gr = row0 + t; bl[t] = (gr < N) ? batch[gr] : -1; }
    poolbuf[t] = 0.f; poolbuf[t + 256] = 0.f;

    // ---- GEMM1: A from LDS, W1 frags direct from global
#pragma unroll
    for (int kb = 0; kb < 2; ++kb)
#pragma unroll
        for (int kc = 0; kc < 2; ++kc) {
            half8 af[4], bfr[4];
#pragma unroll
            for (int j = 0; j < 4; ++j)
                bfr[j] = *(const half8*)(W1t + (size_t)(wc * 64 + j * 16 + lrow) * F
                                         + (kb << 6) + kc * 32 + quad * 8);
#pragma unroll
            for (int i = 0; i < 4; ++i)
                af[i] = *(half8*)(Al + (wr * 64 + i * 16 + lrow) * AL_S
                                  + (kb << 6) + kc * 32 + quad * 8);
#pragma unroll
            for (int i = 0; i < 4; ++i)
#pragma unroll
                for (int j = 0; j < 4; ++j)
                    acc[i][j] = __builtin_amdgcn_mfma_f32_16x16x32_f16(
                        af[i], bfr[j], acc[i][j], 0, 0, 0);
        }

    // ---- t = relu(acc + b1) -> Al
    float bv[4];
#pragma unroll
    for (int j = 0; j < 4; ++j) bv[j] = b1[colbase + j * 16];
    __syncthreads();
#pragma unroll
    for (int i = 0; i < 4; ++i)
#pragma unroll
        for (int r = 0; r < 4; ++r) {
            int row = wr * 64 + i * 16 + quad * 4 + r;
#pragma unroll
            for (int j = 0; j < 4; ++j)
                Al[row * AL_S + colbase + j * 16] =
                    (_Float16)fmaxf(acc[i][j][r] + bv[j], 0.f);
        }

#pragma unroll
    for (int i = 0; i < 4; ++i)
#pragma unroll
        for (int j = 0; j < 4; ++j) acc[i][j] = (f32x4){0.f, 0.f, 0.f, 0.f};

    __syncthreads();

    // ---- GEMM2: t from LDS, W2 frags direct from global
#pragma unroll
    for (int kb = 0; kb < 2; ++kb)
#pragma unroll
        for (int kc = 0; kc < 2; ++kc) {
            half8 af[4], bfr[4];
#pragma unroll
            for (int j = 0; j < 4; ++j)
                bfr[j] = *(const half8*)(W2t + (size_t)(wc * 64 + j * 16 + lrow) * F
                                         + (kb << 6) + kc * 32 + quad * 8);
#pragma unroll
            for (int i = 0; i < 4; ++i)
                af[i] = *(half8*)(Al + (wr * 64 + i * 16 + lrow) * AL_S
                                  + (kb << 6) + kc * 32 + quad * 8);
#pragma unroll
            for (int i = 0; i < 4; ++i)
#pragma unroll
                for (int j = 0; j < 4; ++j)
                    acc[i][j] = __builtin_amdgcn_mfma_f32_16x16x32_f16(
                        af[i], bfr[j], acc[i][j], 0, 0, 0);
        }

    // ---- epilogue: z = relu(acc + b2); stats + raw-z graph pooling; optional Z store
#pragma unroll
    for (int j = 0; j < 4; ++j) bv[j] = b2[colbase + j * 16];

    float s[4], q[4], p[4];
#pragma unroll
    for (int j = 0; j < 4; ++j) { s[j] = 0.f; q[j] = 0.f; p[j] = 0.f; }

    __syncthreads();                    // all GEMM2 reads of Al done
    scratch[t] = 0.f;
    const int g0 = bl[0];
    int gcur = -1;
#pragma unroll
    for (int i = 0; i < 4; ++i)
#pragma unroll
        for (int r = 0; r < 4; ++r) {
            int row = wr * 64 + i * 16 + quad * 4 + r;   // ascending over (i,r)
            bool ok = (row0 + row) < N;
            if (ok) {
                int g = bl[row];
                if (g != gcur) {
                    if (gcur >= 0) {                     // flush partial
                        int slot = gcur - g0;
                        if (slot >= 0 && slot < 4) {
#pragma unroll
                            for (int j = 0; j < 4; ++j)
                                atomicAdd(&poolbuf[slot * F + colbase + j * 16], p[j]);
                        } else {
#pragma unroll
                            for (int j = 0; j < 4; ++j)
                                atomicAdd(&gsumL[(size_t)gcur * F + colbase + j * 16], p[j]);
                        }
#pragma unroll
                        for (int j = 0; j < 4; ++j) p[j] = 0.f;
                    }
                    gcur = g;
                }
            }
#pragma unroll
            for (int j = 0; j < 4; ++j) {
                float u = fmaxf(acc[i][j][r] + bv[j], 0.f);
                Al[row * AL_S + colbase + j * 16] = (_Float16)u;
                if (ok) { s[j] += u; q[j] += u * u; p[j] += u; }
            }
        }
    if (gcur >= 0) {                                     // final flush
        int slot = gcur - g0;
        if (slot >= 0 && slot < 4) {
#pragma unroll
            for (int j = 0; j < 4; ++j)
                atomicAdd(&poolbuf[slot * F + colbase + j * 16], p[j]);
        } else {
#pragma unroll
            for (int j = 0; j < 4; ++j)
                atomicAdd(&gsumL[(size_t)gcur * F + colbase + j * 16], p[j]);
        }
    }
    __syncthreads();                    // Al z-tile + scratch init + poolbuf complete
#pragma unroll
    for (int j = 0; j < 4; ++j) {
        atomicAdd(&scratch[colbase + j * 16], s[j]);
        atomicAdd(&scratch[F + colbase + j * 16], q[j]);
    }
    // drain poolbuf -> gsum (2 slots per thread)
#pragma unroll
    for (int sp = 0; sp < 2; ++sp) {
        int idx = t + sp * 256;
        int slot = idx >> 7, col = idx & 127;
        int g = g0 + slot;
        if (g >= 0 && g < NG)
            atomicAdd(&gsumL[(size_t)g * F + col], poolbuf[idx]);
    }
    if (Z) {
#pragma unroll
        for (int i = 0; i < 8; ++i) {   // coalesced b128 store of z
            int idx = t + (i << 8);
            int row = idx >> 4;
            int k8  = (idx & 15) << 3;
            int gr = row0 + row;
            if (gr < N)
                *(half8*)(Z + (size_t)gr * F + k8) = *(half8*)(Al + row * AL_S + k8);
        }
    }
    __syncthreads();                    // scratch atomics done
    if (t < F) {
        atomicAdd(&stats[t],     scratch[t]);
        atomicAdd(&stats[F + t], scratch[F + t]);
    }
}

// ---- finalize: out[g][L*128+f] = a_Lf * gsum[L][g][f] + cnt_g * c_Lf ----
__global__ __launch_bounds__(384) void k_fin(
    const float* __restrict__ stats, const float* __restrict__ gamma,
    const float* __restrict__ beta, const float* __restrict__ gsum,
    const int* __restrict__ gptr, float invN, float* __restrict__ out)
{
    const int g = blockIdx.x, t = threadIdx.x;
    const int L = t >> 7, f = t & 127;
    float cnt = (float)(gptr[g + 1] - gptr[g]);
    float mean = stats[L * 256 + f] * invN;
    float var  = stats[L * 256 + F + f] * invN - mean * mean;
    float a = gamma[L * F + f] * rsqrtf(var + BN_EPS);
    float c = beta[L * F + f] - mean * a;
    out[(size_t)g * 384 + L * F + f] =
        fmaf(a, gsum[((size_t)L * NG + g) * F + f], cnt * c);
}

extern "C" void kernel_launch(void* const* d_in, const int* in_sizes, int n_in,
                              void* d_out, int out_size, void* d_ws, size_t ws_size,
                              hipStream_t stream)
{
    const float* x     = (const float*)d_in[0];
    const int*   ei    = (const int*)  d_in[1];
    const int*   batch = (const int*)  d_in[2];
    const float* W1    = (const float*)d_in[3];
    const float* b1    = (const float*)d_in[4];
    const float* W2    = (const float*)d_in[5];
    const float* b2    = (const float*)d_in[6];
    const float* gamma = (const float*)d_in[7];
    const float* beta  = (const float*)d_in[8];

    const int N = in_sizes[0] / F;      // 100000
    const int E = in_sizes[1] / 2;      // 1600000
    const int* src = ei;
    const int* dst = ei + E;
    float* out = (float*)d_out;

    const int NB = (N + 1023) >> 10;            // 98 buckets
    const size_t NF = (size_t)N * F;
    _Float16* P0 = (_Float16*)d_ws;             // x16 / Z1
    _Float16* P1 = P0 + NF;                     // Z0 / Z2
    _Float16* Wt = P1 + NF;                     // 6*F*F fp16
    float* stats  = (float*)(Wt + 6 * F * F);   // 768
    int*   gcnt   = (int*)(stats + 768);        // 256 (memset with stats)
    float* gsum   = (float*)(gcnt + 256);       // 3*NG*F
    int*   pairs  = (int*)(gsum + 3 * NG * F);  // NB*CAP (padded, packed local10<<18|src)
    int*   esrc   = pairs + (size_t)NB * CAP;   // NB*CAP (padded)
    int*   rbeg   = esrc + (size_t)NB * CAP;    // N
    int*   rend   = rbeg + N;                   // N
    int*   gptr   = rend + N;                   // NG+1

    // one memset covers stats + gcnt + gsum (contiguous)
    hipMemsetAsync(stats, 0, (768 + 256 + 3 * NG * F) * sizeof(float), stream);

    const int ebk = (E + 4095) / 4096;
    const long n8 = (long)(NF / 8);
    const int prep_grid = (int)(ebk + 51 + (n8 + 255) / 256);

    k_bin_prep<<<prep_grid, 256, 0, stream>>>(src, dst, gcnt, pairs, E, ebk,
                                              W1, W2, Wt, batch, gptr, x, P0, N, n8);
    k_csr<<<NB, 256, 0, stream>>>(pairs, gcnt, rbeg, rend, esrc, N);

    const float invN = 1.0f / (float)N;
    const int mlp_grid = (N + 127) / 128;

    _Float16* Hin = P0;
    _Float16* Zout = P1;
    for (int L = 0; L < 3; ++L) {
        k_gmlp<<<mlp_grid, 256, 0, stream>>>(
            Hin, rbeg, rend, esrc,
            Wt + (size_t)L * F * F, b1 + L * F,
            Wt + (size_t)(3 + L) * F * F, b2 + L * F,
            (L < 2) ? Zout : nullptr,            // last layer: z only pooled, not stored
            N, stats + L * 256,
            L ? stats + (size_t)(L - 1) * 256 : nullptr,
            L ? gamma + (size_t)(L - 1) * F : nullptr,
            L ? beta + (size_t)(L - 1) * F : nullptr, invN,
            batch, gsum + (size_t)L * NG * F);
        _Float16* tmp = Hin; Hin = Zout; Zout = tmp;
    }
    k_fin<<<NG, 384, 0, stream>>>(stats, gamma, beta, gsum, gptr, invN, out);
}